// Round 8
// baseline (249.979 us; speedup 1.0000x reference)
//
#include <hip/hip_runtime.h>
#include <hip/hip_bf16.h>

// Single-head causal attention with value-residual mix.
// B=16, T=2048, C=768, H=64. Inputs/outputs f32; internal compute bf16 MFMA.
// Outputs (concat flat, f32): y=[B,T,64], then v1=[B,T,64].

constexpr int BATCH = 16;
constexpr int TSEQ  = 2048;
constexpr int CEMB  = 768;
constexpr int HS    = 64;
constexpr size_t NTOK    = (size_t)BATCH * TSEQ;  // 32768
constexpr size_t OUTHALF = NTOK * HS;             // 2,097,152 elements

typedef __bf16 bf16x4 __attribute__((ext_vector_type(4)));
typedef __bf16 bf16x8 __attribute__((ext_vector_type(8)));
typedef float  f32x4  __attribute__((ext_vector_type(4)));
typedef float  f32x16 __attribute__((ext_vector_type(16)));
typedef int    i32x4  __attribute__((ext_vector_type(4)));

// ---------------------------------------------------------------------------
// Kernel 0: transpose weights to bf16.
// blocks 0..35: WT[m][h][c] = Wm[c][h];  block 36: WprojT[h'][h]
// ---------------------------------------------------------------------------
__global__ __launch_bounds__(256) void prep_kernel(
    const float* __restrict__ wk, const float* __restrict__ wq,
    const float* __restrict__ wv, const float* __restrict__ wproj,
    __bf16* __restrict__ wt, __bf16* __restrict__ wpt)
{
    __shared__ __bf16 t[64][66];
    const int bid = blockIdx.x;
    if (bid < 36) {
        const int m = bid / 12, c0 = (bid % 12) * 64;
        const float* src = (m == 0) ? wk : (m == 1) ? wq : wv;
        for (int i = threadIdx.x; i < 4096; i += 256) {
            const int c = i >> 6, h = i & 63;
            t[c][h] = (__bf16)src[(size_t)(c0 + c) * HS + h];
        }
        __syncthreads();
        for (int i = threadIdx.x; i < 4096; i += 256) {
            const int h = i >> 6, c = i & 63;
            wt[(size_t)m * HS * CEMB + (size_t)h * CEMB + c0 + c] = t[c][h];
        }
    } else {
        for (int i = threadIdx.x; i < 4096; i += 256) {
            const int h = i >> 6, hp = i & 63;
            t[h][hp] = (__bf16)wproj[i];
        }
        __syncthreads();
        for (int i = threadIdx.x; i < 4096; i += 256) {
            const int hp = i >> 6, h = i & 63;
            wpt[i] = t[h][hp];
        }
    }
}

// ---------------------------------------------------------------------------
// Kernel 1: QKV projection. Round 8: MATRIX-SPLIT grid (512, 3) — blockIdx.y
// picks which of {k,q,v} this block computes for its 64 tokens. 1536 blocks
// -> 4+ blocks/CU (was 512 -> 2/CU, concurrency-starved per Little's law:
// ~5 KB in flight/CU vs ~22 KB needed for BW). Each y-slice re-streams x
// (L3-resident, 96 MB < 256 MB). acc/W register footprint drops to 1/3 ->
// ~60 VGPR, no spill at (256,4). Per-chunk double-buffered LDS staging kept.
// ---------------------------------------------------------------------------
__global__ __launch_bounds__(256, 4) void qkv_kernel(
    const float* __restrict__ x,      // [B*T, 768]
    const float* __restrict__ v1,     // [B*T, 64]
    const __bf16* __restrict__ wt,    // [3][64][768]
    const float* __restrict__ lamb_p,
    __bf16* __restrict__ kk,          // [B*T, 64]
    __bf16* __restrict__ qq,          // [B*T, 64]
    __bf16* __restrict__ vt,          // [B][64][2048]
    float* __restrict__ v1out)        // [B*T, 64] or nullptr
{
    __shared__ __bf16 xl[2][64][88];   // [buf][token][c], stride 88 (16B-aligned)

    const int mm   = blockIdx.y;       // 0=k, 1=q, 2=v
    const int wave = threadIdx.x >> 6;
    const int lane = threadIdx.x & 63;
    const int l16  = lane & 15;
    const int quad = lane >> 4;
    const size_t row0 = (size_t)blockIdx.x * 64;

    // Staging role: thread covers token tok_s, columns [cq*16, cq*16+16).
    const int tok_s = threadIdx.x >> 2;
    const int cq    = threadIdx.x & 3;
    const float* xsrc = x + (row0 + tok_s) * CEMB + cq * 16;

    // This block's W rows: matrix mm, col-tile = wave.
    const __bf16* wb = wt + ((size_t)mm * HS + wave * 16 + l16) * CEMB + quad * 8;

    f32x4 acc[4];
    #pragma unroll
    for (int rt = 0; rt < 4; ++rt) acc[rt] = (f32x4){0.f, 0.f, 0.f, 0.f};

    auto issueX = [&](int chunk, f32x4& a0, f32x4& a1, f32x4& a2, f32x4& a3) {
        const float* xs = xsrc + chunk * 64;
        a0 = *(const f32x4*)(xs);
        a1 = *(const f32x4*)(xs + 4);
        a2 = *(const f32x4*)(xs + 8);
        a3 = *(const f32x4*)(xs + 12);
    };
    auto writeX = [&](int buf, const f32x4& a0, const f32x4& a1,
                      const f32x4& a2, const f32x4& a3) {
        bf16x8 lo, hi;
        #pragma unroll
        for (int i = 0; i < 4; ++i) {
            lo[i] = (__bf16)a0[i]; lo[i + 4] = (__bf16)a1[i];
            hi[i] = (__bf16)a2[i]; hi[i + 4] = (__bf16)a3[i];
        }
        *(bf16x8*)&xl[buf][tok_s][cq * 16]     = lo;
        *(bf16x8*)&xl[buf][tok_s][cq * 16 + 8] = hi;
    };

    // Prologue: chunk 0 staged directly; chunk 1 issued into regs.
    {
        f32x4 t0, t1, t2, t3;
        issueX(0, t0, t1, t2, t3);
        writeX(0, t0, t1, t2, t3);
    }
    f32x4 xa0, xa1, xa2, xa3;
    issueX(1, xa0, xa1, xa2, xa3);
    bf16x8 wc0 = *(const bf16x8*)(wb);
    bf16x8 wc1 = *(const bf16x8*)(wb + 32);
    __syncthreads();

    constexpr int NCH = CEMB / 64;  // 12
    #pragma unroll
    for (int ci = 0; ci < NCH; ++ci) {
        const int buf = ci & 1;
        const bool notlast = (ci + 1 < NCH);

        bf16x8 wn0, wn1;
        if (notlast) {
            wn0 = *(const bf16x8*)(wb + (ci + 1) * 64);
            wn1 = *(const bf16x8*)(wb + (ci + 1) * 64 + 32);
        }

        // Compute on current buffer (gives in-flight xa time to land).
        #pragma unroll
        for (int ks = 0; ks < 2; ++ks) {
            const bf16x8 w = ks ? wc1 : wc0;
            #pragma unroll
            for (int rt = 0; rt < 4; ++rt) {
                const bf16x8 a = *(const bf16x8*)
                    &xl[buf][rt * 16 + l16][ks * 32 + quad * 8];
                acc[rt] = __builtin_amdgcn_mfma_f32_16x16x32_bf16(
                    a, w, acc[rt], 0, 0, 0);
            }
        }

        if (notlast) {
            writeX(buf ^ 1, xa0, xa1, xa2, xa3);   // chunk ci+1 -> other buf
            if (ci + 2 < NCH) issueX(ci + 2, xa0, xa1, xa2, xa3);
            wc0 = wn0; wc1 = wn1;
            __syncthreads();
        }
    }

    // Epilogue. D layout per tile: token = rt*16 + quad*4 + r, col = wave*16+l16.
    const int col = wave * 16 + l16;
    if (mm == 0) {
        #pragma unroll
        for (int rt = 0; rt < 4; ++rt) {
            const size_t tok0 = row0 + rt * 16 + quad * 4;
            #pragma unroll
            for (int r = 0; r < 4; ++r)
                kk[(tok0 + r) * HS + col] = (__bf16)acc[rt][r];
        }
    } else if (mm == 1) {
        #pragma unroll
        for (int rt = 0; rt < 4; ++rt) {
            const size_t tok0 = row0 + rt * 16 + quad * 4;
            #pragma unroll
            for (int r = 0; r < 4; ++r)
                qq[(tok0 + r) * HS + col] = (__bf16)acc[rt][r];
        }
    } else {
        const float lam = lamb_p[0];
        const int b = (int)(row0 >> 11);
        __bf16* vtb = vt + (size_t)b * HS * TSEQ + (size_t)col * TSEQ;
        #pragma unroll
        for (int rt = 0; rt < 4; ++rt) {
            const size_t tok0 = row0 + rt * 16 + quad * 4;
            bf16x4 pk;
            #pragma unroll
            for (int r = 0; r < 4; ++r) {
                const size_t idx = (tok0 + r) * HS + col;
                const float v1v = v1[idx];
                pk[r] = (__bf16)((1.0f - lam) * acc[rt][r] + lam * v1v);
                if (v1out) v1out[idx] = v1v;
            }
            *(bf16x4*)(vtb + (tok0 & 2047)) = pk;
        }
    }
}

// ---------------------------------------------------------------------------
// Kernel 2: flash attention + fused projection — swapped-operand 32x32.
// ROUND-2 PROVEN VERSION (pass-paired (j, 63-j), grid B*32, (256,2),
// K prefetched one tile ahead, V loaded at iteration start). Unchanged.
// ---------------------------------------------------------------------------
__device__ __forceinline__ int pk2(float lo, float hi) {
    unsigned short a = __builtin_bit_cast(unsigned short, (__bf16)lo);
    unsigned short b = __builtin_bit_cast(unsigned short, (__bf16)hi);
    return (int)((((unsigned)b) << 16) | (unsigned)a);
}
// Build a 32x32x16 B-fragment (8 k-consecutive bf16 per lane) from 8 f32
// values in D-register order (rows grpA: p[0..3] = k (0..3)+4hi, grpB:
// p[4..7] = k (8..11)+4hi). Needed: lane(hi,c) holds k = 8*hi + (0..7).
__device__ __forceinline__ bf16x8 make_bfrag(const float* p, int hi) {
    const int a0 = pk2(p[0], p[1]), a1 = pk2(p[2], p[3]);
    const int b0 = pk2(p[4], p[5]), b1 = pk2(p[6], p[7]);
    const int pa0 = __shfl_xor(a0, 32), pa1 = __shfl_xor(a1, 32);
    const int pb0 = __shfl_xor(b0, 32), pb1 = __shfl_xor(b1, 32);
    i32x4 w;
    w[0] = hi ? pb0 : a0;   // k 8hi+0,1
    w[1] = hi ? pb1 : a1;   // k 8hi+2,3
    w[2] = hi ? b0  : pa0;  // k 8hi+4,5
    w[3] = hi ? b1  : pa1;  // k 8hi+6,7
    return __builtin_bit_cast(bf16x8, w);
}

__global__ __launch_bounds__(256, 2) void attn_kernel(
    const __bf16* __restrict__ q,     // [B*T, 64]
    const __bf16* __restrict__ k,     // [B*T, 64]
    const __bf16* __restrict__ vt,    // [B][64][2048]
    const __bf16* __restrict__ wpt,   // [64][64] = Wproj^T
    const float* __restrict__ bproj,  // [64]
    float* __restrict__ y)            // [B*T, 64] f32
{
    __shared__ float olds[4][64][32];   // [wave][h][q]  (bank = q: conflict-free)
    __shared__ float mred[4][32];
    __shared__ float lred[4][32];

    const int b    = blockIdx.x >> 5;
    const int jp   = blockIdx.x & 31;
    const int wave = threadIdx.x >> 6;
    const int lane = threadIdx.x & 63;
    const int l31  = lane & 31;
    const int hi   = lane >> 5;
    const int hi8  = hi * 8;

    const __bf16* kb = k  + (size_t)b * TSEQ * HS;
    const __bf16* vb = vt + (size_t)b * HS * TSEQ;
    const float sc2 = 0.125f * 1.44269504f;  // 1/sqrt(64) * log2(e)

    // Wproj^T A-frags (A[i=h'][k=h], row = lane&31): waves 0,1 only.
    bf16x8 wf[4];
    if (wave < 2) {
        const __bf16* wp = wpt + (size_t)(wave * 32 + l31) * HS + hi8;
        #pragma unroll
        for (int c = 0; c < 4; ++c) wf[c] = *(const bf16x8*)(wp + c * 16);
    }

    for (int pass = 0; pass < 2; ++pass) {
        const int j = pass ? (63 - jp) : jp;
        const size_t tok0 = (size_t)b * TSEQ + (size_t)j * 32;

        // Q B-frags: B[k=h][col=q-row], col = lane&31.
        const __bf16* qp = q + (tok0 + l31) * HS + hi8;
        bf16x8 qf[4];
        #pragma unroll
        for (int c = 0; c < 4; ++c) qf[c] = *(const bf16x8*)(qp + c * 16);

        f32x16 o0, o1;   // O^T accumulators, h in rows, q = lane&31 in cols
        #pragma unroll
        for (int r = 0; r < 16; ++r) { o0[r] = 0.f; o1[r] = 0.f; }
        float m_i = -1e30f, l_i = 0.f;

        bf16x8 kf[4], kn[4];
        if (wave <= j) {
            const __bf16* kp = kb + (size_t)(wave * 32 + l31) * HS + hi8;
            #pragma unroll
            for (int c = 0; c < 4; ++c) kf[c] = *(const bf16x8*)(kp + c * 16);
        }

        for (int t = wave; t <= j; t += 4) {
            const int s0 = t * 32;
            // Issue V loads + next-K prefetch first (independent of MFMA chain).
            bf16x8 vf[4];
            #pragma unroll
            for (int ht = 0; ht < 2; ++ht)
                #pragma unroll
                for (int c2 = 0; c2 < 2; ++c2)
                    vf[ht * 2 + c2] = *(const bf16x8*)(vb
                        + (size_t)(ht * 32 + l31) * TSEQ + s0 + c2 * 16 + hi8);
            if (t + 4 <= j) {
                const __bf16* kp = kb + (size_t)((t + 4) * 32 + l31) * HS + hi8;
                #pragma unroll
                for (int c = 0; c < 4; ++c) kn[c] = *(const bf16x8*)(kp + c * 16);
            }

            // S^T[k_row][q] = mfma(K, Q): rows = keys, col = lane&31 = q-row.
            f32x16 s;
            #pragma unroll
            for (int r = 0; r < 16; ++r) s[r] = 0.f;
            #pragma unroll
            for (int c = 0; c < 4; ++c)
                s = __builtin_amdgcn_mfma_f32_32x32x16_bf16(kf[c], qf[c], s, 0, 0, 0);

            // Scale (+ causal mask on the diagonal tile only).
            float p[16];
            if (t == j) {
                #pragma unroll
                for (int r = 0; r < 16; ++r) {
                    const int krow = (r & 3) + 8 * (r >> 2) + 4 * hi;
                    p[r] = (krow <= l31) ? s[r] * sc2 : -1e30f;
                }
            } else {
                #pragma unroll
                for (int r = 0; r < 16; ++r) p[r] = s[r] * sc2;
            }

            // Tile max: in-lane tree + one cross-half exchange.
            float x0 = fmaxf(p[0], p[1]),   x1 = fmaxf(p[2], p[3]);
            float x2 = fmaxf(p[4], p[5]),   x3 = fmaxf(p[6], p[7]);
            float x4 = fmaxf(p[8], p[9]),   x5 = fmaxf(p[10], p[11]);
            float x6 = fmaxf(p[12], p[13]), x7 = fmaxf(p[14], p[15]);
            float mx = fmaxf(fmaxf(fmaxf(x0, x1), fmaxf(x2, x3)),
                             fmaxf(fmaxf(x4, x5), fmaxf(x6, x7)));
            mx = fmaxf(mx, __shfl_xor(mx, 32));

            // Defer-max (T13): rescale only when max grew by > 8.
            if (!__all(mx <= m_i + 8.f)) {
                const float mn = fmaxf(m_i, mx);
                const float alpha = exp2f(m_i - mn);
                m_i = mn;
                l_i *= alpha;
                #pragma unroll
                for (int r = 0; r < 16; ++r) { o0[r] *= alpha; o1[r] *= alpha; }
            }

            #pragma unroll
            for (int r = 0; r < 16; ++r) p[r] = exp2f(p[r] - m_i);

            float r0 = (p[0] + p[1]) + (p[2] + p[3]);
            float r1 = (p[4] + p[5]) + (p[6] + p[7]);
            float r2 = (p[8] + p[9]) + (p[10] + p[11]);
            float r3 = (p[12] + p[13]) + (p[14] + p[15]);
            float rs = (r0 + r1) + (r2 + r3);
            rs += __shfl_xor(rs, 32);
            l_i += rs;

            // P^T -> B-frags. fb0: keys 0..15, fb1: keys 16..31.
            const bf16x8 fb0 = make_bfrag(&p[0], hi);
            const bf16x8 fb1 = make_bfrag(&p[8], hi);

            // O^T[h][q] += V^T[h][k] * P^T[k][q]; two independent chains.
            o0 = __builtin_amdgcn_mfma_f32_32x32x16_bf16(vf[0], fb0, o0, 0, 0, 0);
            o0 = __builtin_amdgcn_mfma_f32_32x32x16_bf16(vf[1], fb1, o0, 0, 0, 0);
            o1 = __builtin_amdgcn_mfma_f32_32x32x16_bf16(vf[2], fb0, o1, 0, 0, 0);
            o1 = __builtin_amdgcn_mfma_f32_32x32x16_bf16(vf[3], fb1, o1, 0, 0, 0);

            if (t + 4 <= j) {
                #pragma unroll
                for (int c = 0; c < 4; ++c) kf[c] = kn[c];
            }
        }

        // Publish partials: O^T (f32), m, l.
        #pragma unroll
        for (int r = 0; r < 16; ++r) {
            const int row = (r & 3) + 8 * (r >> 2) + 4 * hi;
            olds[wave][row][l31]      = o0[r];
            olds[wave][row + 32][l31] = o1[r];
        }
        if (lane < 32) { mred[wave][lane] = m_i; lred[wave][lane] = l_i; }
        __syncthreads();

        // 4-way merge + fused projection on waves 0,1 (h'-tile = wave).
        if (wave < 2) {
            float mw[4], lw[4];
            #pragma unroll
            for (int w = 0; w < 4; ++w) { mw[w] = mred[w][l31]; lw[w] = lred[w][l31]; }
            const float mg = fmaxf(fmaxf(mw[0], mw[1]), fmaxf(mw[2], mw[3]));
            float g[4], lg = 0.f;
            #pragma unroll
            for (int w = 0; w < 4; ++w) { g[w] = exp2f(mw[w] - mg); lg += g[w] * lw[w]; }
            const float inv = 1.0f / lg;

            float on[32];
            #pragma unroll
            for (int r = 0; r < 16; ++r) {
                const int row = (r & 3) + 8 * (r >> 2) + 4 * hi;
                float a0 = 0.f, a1 = 0.f;
                #pragma unroll
                for (int w = 0; w < 4; ++w) {
                    a0 += g[w] * olds[w][row][l31];
                    a1 += g[w] * olds[w][row + 32][l31];
                }
                on[r]      = a0 * inv;
                on[r + 16] = a1 * inv;
            }

            // Y^T[h'][q] = Wproj^T · O^T ; O^T as B-frags (same rearrange as P).
            f32x16 res;
            #pragma unroll
            for (int r = 0; r < 16; ++r) res[r] = 0.f;
            #pragma unroll
            for (int c = 0; c < 4; ++c) {
                const bf16x8 ob = make_bfrag(&on[c * 8], hi);
                res = __builtin_amdgcn_mfma_f32_32x32x16_bf16(wf[c], ob, res, 0, 0, 0);
            }

            float* yp = y + (tok0 + l31) * HS + wave * 32;
            #pragma unroll
            for (int grp = 0; grp < 4; ++grp) {
                const f32x4 bb = *(const f32x4*)(bproj + wave * 32 + grp * 8 + 4 * hi);
                f32x4 o4;
                #pragma unroll
                for (int rr = 0; rr < 4; ++rr) o4[rr] = res[grp * 4 + rr] + bb[rr];
                *(f32x4*)(yp + grp * 8 + 4 * hi) = o4;
            }
        }
        __syncthreads();
    }
}

// ---------------------------------------------------------------------------
// Kernel 3: v1 passthrough f32->f32 (fallback when ws is too small to move
// the k/vt scratch out of the out1 region).
// ---------------------------------------------------------------------------
__global__ __launch_bounds__(256) void copy_kernel(
    const float* __restrict__ src, float* __restrict__ dst)
{
    const size_t i = ((size_t)blockIdx.x * 256 + threadIdx.x) * 4;
    *(f32x4*)(dst + i) = *(const f32x4*)(src + i);
}

extern "C" void kernel_launch(void* const* d_in, const int* in_sizes, int n_in,
                              void* d_out, int out_size, void* d_ws, size_t ws_size,
                              hipStream_t stream) {
    const float* x     = (const float*)d_in[0];
    const float* v1    = (const float*)d_in[1];
    const float* wk    = (const float*)d_in[2];
    const float* wq    = (const float*)d_in[3];
    const float* wv    = (const float*)d_in[4];
    const float* wproj = (const float*)d_in[5];
    const float* bproj = (const float*)d_in[6];
    const float* lamb  = (const float*)d_in[7];

    float* out = (float*)d_out;

    // ws layout: q | WT | WprojT | (k | vt when ws is large enough)
    __bf16* qp  = (__bf16*)d_ws;
    __bf16* wt  = qp + OUTHALF;
    __bf16* wpt = wt + (size_t)3 * HS * CEMB;
    const size_t base_elems = OUTHALF + (size_t)3 * HS * CEMB + (size_t)HS * HS;
    const size_t need_bytes = (base_elems + 2 * OUTHALF) * sizeof(__bf16);

    __bf16* kp;
    __bf16* vtp;
    float*  v1out;
    const bool fused_v1 = (ws_size >= need_bytes);
    if (fused_v1) {
        kp    = wpt + (size_t)HS * HS;
        vtp   = kp + OUTHALF;
        v1out = out + OUTHALF;          // qkv writes v1 passthrough directly
    } else {
        kp    = (__bf16*)(out + OUTHALF);  // out1 region as bf16 scratch
        vtp   = kp + OUTHALF;
        v1out = nullptr;                   // copy kernel does the passthrough
    }

    prep_kernel<<<dim3(37), dim3(256), 0, stream>>>(wk, wq, wv, wproj, wt, wpt);

    qkv_kernel<<<dim3((int)(NTOK / 64), 3), dim3(256), 0, stream>>>(
        x, v1, wt, lamb, kp, qp, vtp, v1out);

    attn_kernel<<<dim3(BATCH * 32), dim3(256), 0, stream>>>(
        qp, kp, vtp, wpt, bproj, out);

    if (!fused_v1) {
        copy_kernel<<<dim3((int)(OUTHALF / (256 * 4))), dim3(256), 0, stream>>>(
            v1, out + OUTHALF);
    }
}

// Round 9
// 227.983 us; speedup vs baseline: 1.0965x; 1.0965x over previous
//
#include <hip/hip_runtime.h>
#include <hip/hip_bf16.h>

// Single-head causal attention with value-residual mix.
// B=16, T=2048, C=768, H=64. Inputs/outputs f32; internal compute bf16 MFMA.
// Outputs (concat flat, f32): y=[B,T,64], then v1=[B,T,64].

constexpr int BATCH = 16;
constexpr int TSEQ  = 2048;
constexpr int CEMB  = 768;
constexpr int HS    = 64;
constexpr size_t NTOK    = (size_t)BATCH * TSEQ;  // 32768
constexpr size_t OUTHALF = NTOK * HS;             // 2,097,152 elements

typedef __bf16 bf16x4 __attribute__((ext_vector_type(4)));
typedef __bf16 bf16x8 __attribute__((ext_vector_type(8)));
typedef float  f32x4  __attribute__((ext_vector_type(4)));
typedef float  f32x16 __attribute__((ext_vector_type(16)));
typedef int    i32x4  __attribute__((ext_vector_type(4)));

// ---------------------------------------------------------------------------
// Kernel 0: transpose weights to bf16.
// blocks 0..35: WT[m][h][c] = Wm[c][h];  block 36: WprojT[h'][h]
// ---------------------------------------------------------------------------
__global__ __launch_bounds__(256) void prep_kernel(
    const float* __restrict__ wk, const float* __restrict__ wq,
    const float* __restrict__ wv, const float* __restrict__ wproj,
    __bf16* __restrict__ wt, __bf16* __restrict__ wpt)
{
    __shared__ __bf16 t[64][66];
    const int bid = blockIdx.x;
    if (bid < 36) {
        const int m = bid / 12, c0 = (bid % 12) * 64;
        const float* src = (m == 0) ? wk : (m == 1) ? wq : wv;
        for (int i = threadIdx.x; i < 4096; i += 256) {
            const int c = i >> 6, h = i & 63;
            t[c][h] = (__bf16)src[(size_t)(c0 + c) * HS + h];
        }
        __syncthreads();
        for (int i = threadIdx.x; i < 4096; i += 256) {
            const int h = i >> 6, c = i & 63;
            wt[(size_t)m * HS * CEMB + (size_t)h * CEMB + c0 + c] = t[c][h];
        }
    } else {
        for (int i = threadIdx.x; i < 4096; i += 256) {
            const int h = i >> 6, hp = i & 63;
            t[h][hp] = (__bf16)wproj[i];
        }
        __syncthreads();
        for (int i = threadIdx.x; i < 4096; i += 256) {
            const int hp = i >> 6, h = i & 63;
            wpt[i] = t[h][hp];
        }
    }
}

// ---------------------------------------------------------------------------
// Kernel 1: QKV projection. Round 9: back to the round-4/7 decomposition
// (64 tokens/block, all 3 matrices, grid 512, (256,2)) — round 8's matrix
// split tripled FETCH_SIZE (54->151 MB, x re-read from HBM) — but staging
// now uses __builtin_amdgcn_global_load_lds (async, no dest register, so
// the compiler CANNOT sink it like it did the round-7 register pipeline).
// x is staged as raw f32, one wave-instruction per token row (64 lanes x 4B
// = 256B contiguous, perfectly coalesced); LDS rows padded to 68 f32 to
// spread read banks (pad never written -> gload_lds linearity preserved).
// Fragment reads convert f32->bf16 in-register. One barrier per chunk
// (T3-minimal 2-phase); the co-resident 2nd block/CU covers the drain.
// ---------------------------------------------------------------------------
__global__ __launch_bounds__(256, 2) void qkv_kernel(
    const float* __restrict__ x,      // [B*T, 768]
    const float* __restrict__ v1,     // [B*T, 64]
    const __bf16* __restrict__ wt,    // [3][64][768]
    const float* __restrict__ lamb_p,
    __bf16* __restrict__ kk,          // [B*T, 64]
    __bf16* __restrict__ qq,          // [B*T, 64]
    __bf16* __restrict__ vt,          // [B][64][2048]
    float* __restrict__ v1out)        // [B*T, 64] or nullptr
{
    __shared__ float xf[2][64][68];    // [buf][token][channel], 68-f32 stride

    const int wave = threadIdx.x >> 6;
    const int lane = threadIdx.x & 63;
    const int l16  = lane & 15;
    const int quad = lane >> 4;
    const size_t row0 = (size_t)blockIdx.x * 64;

    const __bf16* wbase[3];
    #pragma unroll
    for (int m = 0; m < 3; ++m)
        wbase[m] = wt + ((size_t)m * HS + wave * 16 + l16) * CEMB + quad * 8;

    f32x4 acc[3][4];
    #pragma unroll
    for (int m = 0; m < 3; ++m)
        #pragma unroll
        for (int rt = 0; rt < 4; ++rt)
            acc[m][rt] = (f32x4){0.f, 0.f, 0.f, 0.f};

    // Async stage chunk -> xf[buf]: wave w stages tokens {i*4+w}, one
    // gload_lds per token row (lane l carries channel l, 4 bytes).
    auto stage = [&](int buf, int chunk) {
        #pragma unroll
        for (int i = 0; i < 16; ++i) {
            const int tok = i * 4 + wave;
            const float* g = x + (row0 + tok) * CEMB + chunk * 64 + lane;
            __builtin_amdgcn_global_load_lds(
                (const __attribute__((address_space(1))) unsigned*)g,
                (__attribute__((address_space(3))) unsigned*)&xf[buf][tok][0],
                4, 0, 0);
        }
    };
    auto loadW = [&](int chunk, bf16x8 (&w)[3][2]) {
        #pragma unroll
        for (int m = 0; m < 3; ++m)
            #pragma unroll
            for (int ks = 0; ks < 2; ++ks)
                w[m][ks] = *(const bf16x8*)(wbase[m] + chunk * 64 + ks * 32);
    };
    auto compute = [&](int buf, const bf16x8 (&w)[3][2]) {
        #pragma unroll
        for (int ks = 0; ks < 2; ++ks) {
            bf16x8 a[4];
            #pragma unroll
            for (int rt = 0; rt < 4; ++rt) {
                const float* p = &xf[buf][rt * 16 + l16][ks * 32 + quad * 8];
                const f32x4 u0 = *(const f32x4*)p;
                const f32x4 u1 = *(const f32x4*)(p + 4);
                bf16x8 r;
                #pragma unroll
                for (int j = 0; j < 4; ++j) {
                    r[j] = (__bf16)u0[j]; r[j + 4] = (__bf16)u1[j];
                }
                a[rt] = r;
            }
            #pragma unroll
            for (int m = 0; m < 3; ++m)
                #pragma unroll
                for (int rt = 0; rt < 4; ++rt)
                    acc[m][rt] = __builtin_amdgcn_mfma_f32_16x16x32_bf16(
                        a[rt], w[m][ks], acc[m][rt], 0, 0, 0);
        }
    };

    // Prologue: chunks 0,1 in flight; W for chunk 0.
    stage(0, 0);
    stage(1, 1);
    bf16x8 wc[3][2], wn[3][2];
    loadW(0, wc);
    __syncthreads();   // drains both stages (implicit vmcnt(0))

    constexpr int NCH = CEMB / 64;  // 12
    #pragma unroll
    for (int ci = 0; ci < NCH; ++ci) {
        const int buf = ci & 1;
        const bool notlast = (ci + 1 < NCH);
        if (notlast) loadW(ci + 1, wn);
        compute(buf, wc);
        if (notlast) {
            #pragma unroll
            for (int m = 0; m < 3; ++m)
                #pragma unroll
                for (int ks = 0; ks < 2; ++ks) wc[m][ks] = wn[m][ks];
            __syncthreads();                 // buf free + chunk ci+1 landed
            if (ci + 2 < NCH) stage(buf, ci + 2);  // async, in flight next iter
        }
    }

    // Epilogue. D layout per tile: token = rt*16 + quad*4 + r, col = wave*16+l16.
    const float lam = lamb_p[0];
    const int col = wave * 16 + l16;
    const int b  = (int)(row0 >> 11);
    __bf16* vtb = vt + (size_t)b * HS * TSEQ + (size_t)col * TSEQ;
    #pragma unroll
    for (int rt = 0; rt < 4; ++rt) {
        const size_t tok0 = row0 + rt * 16 + quad * 4;
        bf16x4 pk;
        #pragma unroll
        for (int r = 0; r < 4; ++r) {
            const size_t idx = (tok0 + r) * HS + col;
            const float v1v = v1[idx];
            kk[idx] = (__bf16)acc[0][rt][r];
            qq[idx] = (__bf16)acc[1][rt][r];
            pk[r] = (__bf16)((1.0f - lam) * acc[2][rt][r] + lam * v1v);
            if (v1out) v1out[idx] = v1v;
        }
        *(bf16x4*)(vtb + (tok0 & 2047)) = pk;
    }
}

// ---------------------------------------------------------------------------
// Kernel 2: flash attention + fused projection — swapped-operand 32x32.
// ROUND-2 PROVEN VERSION (pass-paired (j, 63-j), grid B*32, (256,2),
// K prefetched one tile ahead, V loaded at iteration start). Unchanged.
// ---------------------------------------------------------------------------
__device__ __forceinline__ int pk2(float lo, float hi) {
    unsigned short a = __builtin_bit_cast(unsigned short, (__bf16)lo);
    unsigned short b = __builtin_bit_cast(unsigned short, (__bf16)hi);
    return (int)((((unsigned)b) << 16) | (unsigned)a);
}
// Build a 32x32x16 B-fragment (8 k-consecutive bf16 per lane) from 8 f32
// values in D-register order (rows grpA: p[0..3] = k (0..3)+4hi, grpB:
// p[4..7] = k (8..11)+4hi). Needed: lane(hi,c) holds k = 8*hi + (0..7).
__device__ __forceinline__ bf16x8 make_bfrag(const float* p, int hi) {
    const int a0 = pk2(p[0], p[1]), a1 = pk2(p[2], p[3]);
    const int b0 = pk2(p[4], p[5]), b1 = pk2(p[6], p[7]);
    const int pa0 = __shfl_xor(a0, 32), pa1 = __shfl_xor(a1, 32);
    const int pb0 = __shfl_xor(b0, 32), pb1 = __shfl_xor(b1, 32);
    i32x4 w;
    w[0] = hi ? pb0 : a0;   // k 8hi+0,1
    w[1] = hi ? pb1 : a1;   // k 8hi+2,3
    w[2] = hi ? b0  : pa0;  // k 8hi+4,5
    w[3] = hi ? b1  : pa1;  // k 8hi+6,7
    return __builtin_bit_cast(bf16x8, w);
}

__global__ __launch_bounds__(256, 2) void attn_kernel(
    const __bf16* __restrict__ q,     // [B*T, 64]
    const __bf16* __restrict__ k,     // [B*T, 64]
    const __bf16* __restrict__ vt,    // [B][64][2048]
    const __bf16* __restrict__ wpt,   // [64][64] = Wproj^T
    const float* __restrict__ bproj,  // [64]
    float* __restrict__ y)            // [B*T, 64] f32
{
    __shared__ float olds[4][64][32];   // [wave][h][q]  (bank = q: conflict-free)
    __shared__ float mred[4][32];
    __shared__ float lred[4][32];

    const int b    = blockIdx.x >> 5;
    const int jp   = blockIdx.x & 31;
    const int wave = threadIdx.x >> 6;
    const int lane = threadIdx.x & 63;
    const int l31  = lane & 31;
    const int hi   = lane >> 5;
    const int hi8  = hi * 8;

    const __bf16* kb = k  + (size_t)b * TSEQ * HS;
    const __bf16* vb = vt + (size_t)b * HS * TSEQ;
    const float sc2 = 0.125f * 1.44269504f;  // 1/sqrt(64) * log2(e)

    // Wproj^T A-frags (A[i=h'][k=h], row = lane&31): waves 0,1 only.
    bf16x8 wf[4];
    if (wave < 2) {
        const __bf16* wp = wpt + (size_t)(wave * 32 + l31) * HS + hi8;
        #pragma unroll
        for (int c = 0; c < 4; ++c) wf[c] = *(const bf16x8*)(wp + c * 16);
    }

    for (int pass = 0; pass < 2; ++pass) {
        const int j = pass ? (63 - jp) : jp;
        const size_t tok0 = (size_t)b * TSEQ + (size_t)j * 32;

        // Q B-frags: B[k=h][col=q-row], col = lane&31.
        const __bf16* qp = q + (tok0 + l31) * HS + hi8;
        bf16x8 qf[4];
        #pragma unroll
        for (int c = 0; c < 4; ++c) qf[c] = *(const bf16x8*)(qp + c * 16);

        f32x16 o0, o1;   // O^T accumulators, h in rows, q = lane&31 in cols
        #pragma unroll
        for (int r = 0; r < 16; ++r) { o0[r] = 0.f; o1[r] = 0.f; }
        float m_i = -1e30f, l_i = 0.f;

        bf16x8 kf[4], kn[4];
        if (wave <= j) {
            const __bf16* kp = kb + (size_t)(wave * 32 + l31) * HS + hi8;
            #pragma unroll
            for (int c = 0; c < 4; ++c) kf[c] = *(const bf16x8*)(kp + c * 16);
        }

        for (int t = wave; t <= j; t += 4) {
            const int s0 = t * 32;
            // Issue V loads + next-K prefetch first (independent of MFMA chain).
            bf16x8 vf[4];
            #pragma unroll
            for (int ht = 0; ht < 2; ++ht)
                #pragma unroll
                for (int c2 = 0; c2 < 2; ++c2)
                    vf[ht * 2 + c2] = *(const bf16x8*)(vb
                        + (size_t)(ht * 32 + l31) * TSEQ + s0 + c2 * 16 + hi8);
            if (t + 4 <= j) {
                const __bf16* kp = kb + (size_t)((t + 4) * 32 + l31) * HS + hi8;
                #pragma unroll
                for (int c = 0; c < 4; ++c) kn[c] = *(const bf16x8*)(kp + c * 16);
            }

            // S^T[k_row][q] = mfma(K, Q): rows = keys, col = lane&31 = q-row.
            f32x16 s;
            #pragma unroll
            for (int r = 0; r < 16; ++r) s[r] = 0.f;
            #pragma unroll
            for (int c = 0; c < 4; ++c)
                s = __builtin_amdgcn_mfma_f32_32x32x16_bf16(kf[c], qf[c], s, 0, 0, 0);

            // Scale (+ causal mask on the diagonal tile only).
            float p[16];
            if (t == j) {
                #pragma unroll
                for (int r = 0; r < 16; ++r) {
                    const int krow = (r & 3) + 8 * (r >> 2) + 4 * hi;
                    p[r] = (krow <= l31) ? s[r] * sc2 : -1e30f;
                }
            } else {
                #pragma unroll
                for (int r = 0; r < 16; ++r) p[r] = s[r] * sc2;
            }

            // Tile max: in-lane tree + one cross-half exchange.
            float x0 = fmaxf(p[0], p[1]),   x1 = fmaxf(p[2], p[3]);
            float x2 = fmaxf(p[4], p[5]),   x3 = fmaxf(p[6], p[7]);
            float x4 = fmaxf(p[8], p[9]),   x5 = fmaxf(p[10], p[11]);
            float x6 = fmaxf(p[12], p[13]), x7 = fmaxf(p[14], p[15]);
            float mx = fmaxf(fmaxf(fmaxf(x0, x1), fmaxf(x2, x3)),
                             fmaxf(fmaxf(x4, x5), fmaxf(x6, x7)));
            mx = fmaxf(mx, __shfl_xor(mx, 32));

            // Defer-max (T13): rescale only when max grew by > 8.
            if (!__all(mx <= m_i + 8.f)) {
                const float mn = fmaxf(m_i, mx);
                const float alpha = exp2f(m_i - mn);
                m_i = mn;
                l_i *= alpha;
                #pragma unroll
                for (int r = 0; r < 16; ++r) { o0[r] *= alpha; o1[r] *= alpha; }
            }

            #pragma unroll
            for (int r = 0; r < 16; ++r) p[r] = exp2f(p[r] - m_i);

            float r0 = (p[0] + p[1]) + (p[2] + p[3]);
            float r1 = (p[4] + p[5]) + (p[6] + p[7]);
            float r2 = (p[8] + p[9]) + (p[10] + p[11]);
            float r3 = (p[12] + p[13]) + (p[14] + p[15]);
            float rs = (r0 + r1) + (r2 + r3);
            rs += __shfl_xor(rs, 32);
            l_i += rs;

            // P^T -> B-frags. fb0: keys 0..15, fb1: keys 16..31.
            const bf16x8 fb0 = make_bfrag(&p[0], hi);
            const bf16x8 fb1 = make_bfrag(&p[8], hi);

            // O^T[h][q] += V^T[h][k] * P^T[k][q]; two independent chains.
            o0 = __builtin_amdgcn_mfma_f32_32x32x16_bf16(vf[0], fb0, o0, 0, 0, 0);
            o0 = __builtin_amdgcn_mfma_f32_32x32x16_bf16(vf[1], fb1, o0, 0, 0, 0);
            o1 = __builtin_amdgcn_mfma_f32_32x32x16_bf16(vf[2], fb0, o1, 0, 0, 0);
            o1 = __builtin_amdgcn_mfma_f32_32x32x16_bf16(vf[3], fb1, o1, 0, 0, 0);

            if (t + 4 <= j) {
                #pragma unroll
                for (int c = 0; c < 4; ++c) kf[c] = kn[c];
            }
        }

        // Publish partials: O^T (f32), m, l.
        #pragma unroll
        for (int r = 0; r < 16; ++r) {
            const int row = (r & 3) + 8 * (r >> 2) + 4 * hi;
            olds[wave][row][l31]      = o0[r];
            olds[wave][row + 32][l31] = o1[r];
        }
        if (lane < 32) { mred[wave][lane] = m_i; lred[wave][lane] = l_i; }
        __syncthreads();

        // 4-way merge + fused projection on waves 0,1 (h'-tile = wave).
        if (wave < 2) {
            float mw[4], lw[4];
            #pragma unroll
            for (int w = 0; w < 4; ++w) { mw[w] = mred[w][l31]; lw[w] = lred[w][l31]; }
            const float mg = fmaxf(fmaxf(mw[0], mw[1]), fmaxf(mw[2], mw[3]));
            float g[4], lg = 0.f;
            #pragma unroll
            for (int w = 0; w < 4; ++w) { g[w] = exp2f(mw[w] - mg); lg += g[w] * lw[w]; }
            const float inv = 1.0f / lg;

            float on[32];
            #pragma unroll
            for (int r = 0; r < 16; ++r) {
                const int row = (r & 3) + 8 * (r >> 2) + 4 * hi;
                float a0 = 0.f, a1 = 0.f;
                #pragma unroll
                for (int w = 0; w < 4; ++w) {
                    a0 += g[w] * olds[w][row][l31];
                    a1 += g[w] * olds[w][row + 32][l31];
                }
                on[r]      = a0 * inv;
                on[r + 16] = a1 * inv;
            }

            // Y^T[h'][q] = Wproj^T · O^T ; O^T as B-frags (same rearrange as P).
            f32x16 res;
            #pragma unroll
            for (int r = 0; r < 16; ++r) res[r] = 0.f;
            #pragma unroll
            for (int c = 0; c < 4; ++c) {
                const bf16x8 ob = make_bfrag(&on[c * 8], hi);
                res = __builtin_amdgcn_mfma_f32_32x32x16_bf16(wf[c], ob, res, 0, 0, 0);
            }

            float* yp = y + (tok0 + l31) * HS + wave * 32;
            #pragma unroll
            for (int grp = 0; grp < 4; ++grp) {
                const f32x4 bb = *(const f32x4*)(bproj + wave * 32 + grp * 8 + 4 * hi);
                f32x4 o4;
                #pragma unroll
                for (int rr = 0; rr < 4; ++rr) o4[rr] = res[grp * 4 + rr] + bb[rr];
                *(f32x4*)(yp + grp * 8 + 4 * hi) = o4;
            }
        }
        __syncthreads();
    }
}

// ---------------------------------------------------------------------------
// Kernel 3: v1 passthrough f32->f32 (fallback when ws is too small to move
// the k/vt scratch out of the out1 region).
// ---------------------------------------------------------------------------
__global__ __launch_bounds__(256) void copy_kernel(
    const float* __restrict__ src, float* __restrict__ dst)
{
    const size_t i = ((size_t)blockIdx.x * 256 + threadIdx.x) * 4;
    *(f32x4*)(dst + i) = *(const f32x4*)(src + i);
}

extern "C" void kernel_launch(void* const* d_in, const int* in_sizes, int n_in,
                              void* d_out, int out_size, void* d_ws, size_t ws_size,
                              hipStream_t stream) {
    const float* x     = (const float*)d_in[0];
    const float* v1    = (const float*)d_in[1];
    const float* wk    = (const float*)d_in[2];
    const float* wq    = (const float*)d_in[3];
    const float* wv    = (const float*)d_in[4];
    const float* wproj = (const float*)d_in[5];
    const float* bproj = (const float*)d_in[6];
    const float* lamb  = (const float*)d_in[7];

    float* out = (float*)d_out;

    // ws layout: q | WT | WprojT | (k | vt when ws is large enough)
    __bf16* qp  = (__bf16*)d_ws;
    __bf16* wt  = qp + OUTHALF;
    __bf16* wpt = wt + (size_t)3 * HS * CEMB;
    const size_t base_elems = OUTHALF + (size_t)3 * HS * CEMB + (size_t)HS * HS;
    const size_t need_bytes = (base_elems + 2 * OUTHALF) * sizeof(__bf16);

    __bf16* kp;
    __bf16* vtp;
    float*  v1out;
    const bool fused_v1 = (ws_size >= need_bytes);
    if (fused_v1) {
        kp    = wpt + (size_t)HS * HS;
        vtp   = kp + OUTHALF;
        v1out = out + OUTHALF;          // qkv writes v1 passthrough directly
    } else {
        kp    = (__bf16*)(out + OUTHALF);  // out1 region as bf16 scratch
        vtp   = kp + OUTHALF;
        v1out = nullptr;                   // copy kernel does the passthrough
    }

    prep_kernel<<<dim3(37), dim3(256), 0, stream>>>(wk, wq, wv, wproj, wt, wpt);

    qkv_kernel<<<dim3((int)(NTOK / 64)), dim3(256), 0, stream>>>(
        x, v1, wt, lamb, kp, qp, vtp, v1out);

    attn_kernel<<<dim3(BATCH * 32), dim3(256), 0, stream>>>(
        qp, kp, vtp, wpt, bproj, out);

    if (!fused_v1) {
        copy_kernel<<<dim3((int)(OUTHALF / (256 * 4))), dim3(256), 0, stream>>>(
            v1, out + OUTHALF);
    }
}